// Round 14
// baseline (993.105 us; speedup 1.0000x reference)
//
#include <hip/hip_runtime.h>
#include <hip/hip_cooperative_groups.h>

#pragma clang fp contract(off)

namespace cg = cooperative_groups;

typedef unsigned long long u64;
typedef unsigned int u32;
typedef unsigned short u16;

#define BATCH 8
#define NA 131072
#define NSEL 6000
#define NW 94                 // ceil(6000/64)
#define NPAD (NW * 64)        // 6016
#define CAND_CAP 8192
#define PROP 1000
#define SCAP 1024             // sparse entries cap per (batch, source word)
#define LDSE 6016             // sparse entries staged in LDS
#define CELLCAP 256           // boxes per 8x8 grid cell (mean ~94)
#define LARGECAP 1024         // "large" boxes per batch (dim > 1/8)
#define LTHR 0.125f

// ---- workspace layout (bytes); [0, MEMSET_BYTES) zeroed in phase 0 ----
#define OFF_HIST     0            // BATCH*257*4 = 8224
#define OFF_TBUCK    8960         // BATCH*4
#define OFF_BSTART   9216         // 8224 -> 17440
#define OFF_BFILL    17664        // 8224 -> 25888
#define OFF_SCNT     26112        // 3008 -> 29120
#define OFF_CELLCNT  29184        // BATCH*65*4 = 2080 -> 31264
#define OFF_DIAGT    31296        // BATCH*94*64*8 = 385024 -> 416320
#define MEMSET_BYTES 416320
#define OFF_CAND     416768      // BATCH*8192*8 = 524288 -> 941056
#define OFF_BOXES    941056      // BATCH*6016*16 = 770048 -> 1711104
#define OFF_KEEP     1711104     // 6016 -> 1717120
#define OFF_BASE     1717120     // 3008 -> 1720128
#define OFF_CELLLIST 1720128     // BATCH*64*CELLCAP*2 = 262144 -> 1982272
#define OFF_LARGE    1982272     // BATCH*LARGECAP*2 = 16384 -> 1998656
#define OFF_SENT     1998656     // BATCH*94*SCAP*16 = 12320768 -> 14319424 (~13.7MB)

__device__ __forceinline__ int bucket_of(u32 bits) {
  u32 hi = bits >> 16;
  if (hi >= 0x3E80u && hi < 0x3F80u) return (int)(hi - 0x3E80u);
  if (hi >= 0x3F80u && hi < 0x8000u) return 255;
  return -1;
}

// "RN32(inter / max(uni,1e-12)) > 0.7f" without fp32 divide, bit-exact:
// M=0x1.666667p-1 is the 0.7f/nextafter midpoint; RN32(t)>0.7f <=> t>=M;
// a/b>=M <=> a>=M*b, exact in fp64 (25-bit x 24-bit product).
__device__ __forceinline__ bool iou_gt(float4 A, float4 B, float areaA, float areaB) {
  float iy = fminf(A.z, B.z) - fmaxf(A.x, B.x);
  float ix = fminf(A.w, B.w) - fmaxf(A.y, B.y);
  float inter = fmaxf(iy, 0.0f) * fmaxf(ix, 0.0f);
  float uni = (areaA + areaB) - inter;
  float uc = fmaxf(uni, 1e-12f);
  return (double)inter >= 0x1.666667p-1 * (double)uc;
}

__device__ __forceinline__ void emit_pair(int b, int ra, int rb, u64* diagT,
                                          u64* sent, int* scnt) {
  int src = min(ra, rb), dst = max(ra, rb);
  int wsrc = src >> 6, wdst = dst >> 6;
  if (wsrc == wdst) {
    atomicOr(&diagT[((size_t)b * NW + wdst) * 64 + (dst & 63)], 1ULL << (src & 63));
  } else {
    int e = atomicAdd(&scnt[b * NW + wsrc], 1);
    if (e < SCAP) {
      u64* p = sent + ((size_t)(b * NW + wsrc) * SCAP + e) * 2;
      p[0] = 1ULL << (dst & 63);
      p[1] = ((u64)(dst >> 6) << 8) | (u64)(src & 63);
    }
  }
}

__device__ __forceinline__ u64 shfl_xor_u64(u64 v, int lanemask) {
  u32 lo = (u32)v, hi = (u32)(v >> 32);
  lo = (u32)__shfl_xor((int)lo, lanemask);
  hi = (u32)__shfl_xor((int)hi, lanemask);
  return ((u64)hi << 32) | (u64)lo;
}

struct PairLds {
  float4 As[CELLCAP];
  float Aas[CELLCAP];
  int Ais[CELLCAP];
};
struct NmsLds {
  u64 diag_s[NW * 64];  // 48128
  u64 remv[NW];
  u64 ebits[LDSE];      // 48128
  u32 emeta[LDSE];      // 24064
  int cw[NW];
  int prefix[NW + 1];
};
union ShMem {
  int hist[257];
  u64 sortbuf[1024];
  PairLds pc;
  NmsLds nms;
};

// ONE cooperative kernel: 256 blocks x 1024 threads (1 block/CU; LDS ~122KB).
// Phases split by threadfence+grid.sync. All phase algorithms are the
// previously-validated per-kernel versions.
__global__ __launch_bounds__(1024) void mega_kernel(const float* __restrict__ probs,
                                                    const float* __restrict__ deltas,
                                                    const float* __restrict__ anchors,
                                                    char* __restrict__ ws,
                                                    float4* __restrict__ out) {
  cg::grid_group grid = cg::this_grid();
  __shared__ ShMem sh;
  int tid = threadIdx.x, bid = blockIdx.x;
  int gtid = bid * 1024 + tid;
  const int gstride = 256 * 1024;

  int* hist = (int*)(ws + OFF_HIST);
  int* tbuck = (int*)(ws + OFF_TBUCK);
  int* bstart = (int*)(ws + OFF_BSTART);
  int* bfill = (int*)(ws + OFF_BFILL);
  int* scnt = (int*)(ws + OFF_SCNT);
  int* cellCnt = (int*)(ws + OFF_CELLCNT);
  u64* diagT = (u64*)(ws + OFF_DIAGT);
  u64* cand = (u64*)(ws + OFF_CAND);
  float4* boxes = (float4*)(ws + OFF_BOXES);
  u64* keepmask = (u64*)(ws + OFF_KEEP);
  int* basecnt = (int*)(ws + OFF_BASE);
  u16* cellList = (u16*)(ws + OFF_CELLLIST);
  u16* largeList = (u16*)(ws + OFF_LARGE);
  u64* sent = (u64*)(ws + OFF_SENT);

  // ---- phase 0: zero counters + diagT + output ----
  for (int i = gtid; i < MEMSET_BYTES / 4; i += gstride) ((u32*)ws)[i] = 0u;
  float* outf = (float*)out;
  for (int i = gtid; i < BATCH * PROP * 4; i += gstride) outf[i] = 0.f;
  __threadfence();
  grid.sync();

  // ---- phase 1: histogram (block = (batch, chunk of 4096)) ----
  {
    int b = bid & 7, chunk = bid >> 3;
    for (int i = tid; i < 257; i += 1024) sh.hist[i] = 0;
    __syncthreads();
    int a0 = chunk * 4096;
    for (int a = a0 + tid; a < a0 + 4096; a += 1024) {
      float sc = probs[((size_t)b * NA + a) * 2 + 1];
      int bk = bucket_of(__float_as_uint(sc));
      atomicAdd(&sh.hist[bk < 0 ? 256 : bk], 1);
    }
    __syncthreads();
    for (int i = tid; i < 257; i += 1024)
      if (sh.hist[i]) atomicAdd(&hist[b * 257 + i], sh.hist[i]);
  }
  __threadfence();
  grid.sync();

  // ---- phase 2: select threshold + prefix (blocks 0..7) ----
  if (bid < 8) {
    int b = bid;
    if (tid < 256) sh.hist[tid] = hist[b * 257 + tid];
    __syncthreads();
    if (tid == 0) {
      int run = 0, t = 0;
      bool found = false;
      for (int v = 255; v >= 0; --v) {
        bstart[b * 257 + v] = run;
        run += sh.hist[v];
        if (!found && run >= NSEL) { t = v; found = true; }
      }
      tbuck[b] = t;
    }
  }
  __threadfence();
  grid.sync();

  // ---- phase 3: gather/scatter into bucket segments ----
  {
    int b = bid & 7, chunk = bid >> 3;
    int tb = tbuck[b];
    int a0 = chunk * 4096;
    for (int a = a0 + tid; a < a0 + 4096; a += 1024) {
      float sc = probs[((size_t)b * NA + a) * 2 + 1];
      u32 bits = __float_as_uint(sc);
      int bk = bucket_of(bits);
      if (bk >= tb) {
        int pos = bstart[b * 257 + bk] + atomicAdd(&bfill[b * 257 + bk], 1);
        if (pos < CAND_CAP)
          cand[(size_t)b * CAND_CAP + pos] =
              ((u64)bits << 32) | (u64)(0xFFFFFFFFu - (u32)a);
      }
    }
  }
  __threadfence();
  grid.sync();

  // ---- phase 4: per-(batch,bucket-slot) bitonic sort, 1 elem/thread ----
  for (int u = bid; u < 512; u += 256) {
    int b = u >> 6;
    int v = tbuck[b] + (u & 63);
    if (v > 255) continue;
    int cnt = min(bfill[b * 257 + v], 1024);
    int start = bstart[b * 257 + v];
    cnt = min(cnt, CAND_CAP - start);
    if (cnt <= 0) continue;
    u64* seg = cand + (size_t)b * CAND_CAP + start;
    u64 x = (tid < cnt) ? seg[tid] : 0ULL;
    for (int k = 2; k <= 64; k <<= 1) {
      for (int j = k >> 1; j >= 1; j >>= 1) {
        u64 pv = shfl_xor_u64(x, j);
        bool takemax = (((tid & j) == 0) == ((tid & k) == 0));
        u64 mx = x > pv ? x : pv;
        u64 mn = x < pv ? x : pv;
        x = takemax ? mx : mn;
      }
    }
    __syncthreads();  // protect sortbuf reuse across u iterations
    sh.sortbuf[tid] = x;
    __syncthreads();
    for (int k = 128; k <= 1024; k <<= 1) {
      for (int j = k >> 1; j >= 64; j >>= 1) {
        if (tid < 512) {
          int i = ((tid & ~(j - 1)) << 1) | (tid & (j - 1));
          int ixj = i | j;
          u64 a = sh.sortbuf[i], c = sh.sortbuf[ixj];
          bool up = ((i & k) == 0);
          if (up ? (a < c) : (a > c)) { sh.sortbuf[i] = c; sh.sortbuf[ixj] = a; }
        }
        __syncthreads();
      }
      x = sh.sortbuf[tid];
      for (int j = 32; j >= 1; j >>= 1) {
        u64 pv = shfl_xor_u64(x, j);
        bool takemax = (((tid & j) == 0) == ((tid & k) == 0));
        u64 mx = x > pv ? x : pv;
        u64 mn = x < pv ? x : pv;
        x = takemax ? mx : mn;
      }
      __syncthreads();
      sh.sortbuf[tid] = x;
      __syncthreads();
    }
    if (tid < cnt) seg[tid] = sh.sortbuf[tid];
  }
  __threadfence();
  grid.sync();

  // ---- phase 5: decode + clip + spatial bin ----
  for (int t = gtid; t < BATCH * NPAD; t += gstride) {
    int b = t / NPAD, r = t - b * NPAD;
    float4 o = {0.f, 0.f, 0.f, 0.f};
    if (r < NSEL) {
      u64 key = cand[(size_t)b * CAND_CAP + r];
      u32 idx = 0xFFFFFFFFu - (u32)(key & 0xFFFFFFFFu);
      if (idx < NA) {
        const float* anc = anchors + ((size_t)b * NA + idx) * 4;
        const float* dl = deltas + ((size_t)b * NA + idx) * 4;
        float y1 = anc[0], x1 = anc[1], y2 = anc[2], x2 = anc[3];
        float dy = dl[0] * 0.1f, dx = dl[1] * 0.1f;
        float dh = dl[2] * 0.2f, dw = dl[3] * 0.2f;
        float h = y2 - y1, w = x2 - x1;
        float cy = y1 + 0.5f * h + dy * h;
        float cx = x1 + 0.5f * w + dx * w;
        h = h * expf(dh);
        w = w * expf(dw);
        float ny1 = cy - 0.5f * h, nx1 = cx - 0.5f * w;
        float ny2 = ny1 + h, nx2 = nx1 + w;
        o.x = fminf(fmaxf(ny1, 0.f), 1.f);
        o.y = fminf(fmaxf(nx1, 0.f), 1.f);
        o.z = fminf(fmaxf(ny2, 0.f), 1.f);
        o.w = fminf(fmaxf(nx2, 0.f), 1.f);
      }
    }
    boxes[(size_t)b * NPAD + r] = o;
    if (r < NSEL) {
      float bh = o.z - o.x, bw = o.w - o.y;
      if (bh > LTHR || bw > LTHR) {
        int pos = atomicAdd(&cellCnt[b * 65 + 64], 1);
        if (pos < LARGECAP) largeList[b * LARGECAP + pos] = (u16)r;
      } else {
        int gy = min(7, max(0, (int)((o.x + o.z) * 4.0f)));
        int gx = min(7, max(0, (int)((o.y + o.w) * 4.0f)));
        int cell = gy * 8 + gx;
        int pos = atomicAdd(&cellCnt[b * 65 + cell], 1);
        if (pos < CELLCAP) cellList[((size_t)b * 64 + cell) * CELLCAP + pos] = (u16)r;
      }
    }
  }
  __threadfence();
  grid.sync();

  // ---- phase 6: pair tests (512 cell units, 2/block) + large boxes ----
  for (int u = bid; u < 512; u += 256) {
    int b = u >> 6, c = u & 63;
    int cy = c >> 3, cx = c & 7;
    __syncthreads();  // protect sh.pc reuse across u iterations
    int nA = min(cellCnt[b * 65 + c], CELLCAP);
    for (int i = tid; i < nA; i += 1024) {
      int r = cellList[((size_t)b * 64 + c) * CELLCAP + i];
      float4 bx = boxes[(size_t)b * NPAD + r];
      sh.pc.As[i] = bx;
      sh.pc.Aas[i] = (bx.z - bx.x) * (bx.w - bx.y);
      sh.pc.Ais[i] = r;
    }
    // concatenated j-list: [self | E | SW | S | SE]
    const int dys[4] = {0, 1, 1, 1};
    const int dxs[4] = {1, -1, 0, 1};
    int ncell[4], off[5];
    off[0] = 0;
    for (int k = 0; k < 4; ++k) {
      int ny = cy + dys[k], nx = cx + dxs[k];
      int nc = -1, cnt = 0;
      if (ny < 8 && nx >= 0 && nx < 8) {
        nc = ny * 8 + nx;
        cnt = min(cellCnt[b * 65 + nc], CELLCAP);
      }
      ncell[k] = nc;
      off[k + 1] = off[k] + cnt;
    }
    int nL = nA + off[4];  // <= 256 + 1024 = 1280
    // register-owned j's: jj = tid, tid+1024
    float4 jb[2];
    float ja[2];
    int jr[2], sidx[2];
    int nown = 0;
    for (int jj = tid; jj < nL && nown < 2; jj += 1024) {
      int r, si = -1;
      if (jj < nA) {
        r = cellList[((size_t)b * 64 + c) * CELLCAP + jj];
        si = jj;
      } else {
        int t2 = jj - nA;
        int k = 0;
        while (t2 >= off[k + 1]) ++k;
        r = cellList[((size_t)b * 64 + ncell[k]) * CELLCAP + (t2 - off[k])];
      }
      float4 bx = boxes[(size_t)b * NPAD + r];
      jb[nown] = bx;
      ja[nown] = (bx.z - bx.x) * (bx.w - bx.y);
      jr[nown] = r;
      sidx[nown] = si;
      ++nown;
    }
    __syncthreads();
    if (nown > 0) {
      for (int i = 0; i < nA; ++i) {
        float4 ab = sh.pc.As[i];  // wave-uniform address -> LDS broadcast
        float aa = sh.pc.Aas[i];
        int ar = sh.pc.Ais[i];
#pragma unroll
        for (int q = 0; q < 2; ++q) {
          if (q < nown) {
            bool ok = (sidx[q] < 0) || (i < sidx[q]);
            if (ok && iou_gt(ab, jb[q], aa, ja[q]))
              emit_pair(b, ar, jr[q], diagT, sent, scnt);
          }
        }
      }
    }
  }
  // large boxes vs all (large-large deduped: lower index owns pair)
  for (int b = 0; b < BATCH; ++b) {
    int nLg = min(cellCnt[b * 65 + 64], LARGECAP);
    int tot = nLg * NPAD;
    for (int t = gtid; t < tot; t += gstride) {
      int li = t / NPAD;
      int j = t - li * NPAD;
      int L = largeList[b * LARGECAP + li];
      if (j == L || j >= NSEL) continue;
      float4 jbx = boxes[(size_t)b * NPAD + j];
      float jh = jbx.z - jbx.x, jw = jbx.w - jbx.y;
      if ((jh > LTHR || jw > LTHR) && j < L) continue;
      float4 Lb = boxes[(size_t)b * NPAD + L];
      float La = (Lb.z - Lb.x) * (Lb.w - Lb.y);
      float jA = jh * jw;
      if (iou_gt(Lb, jbx, La, jA)) emit_pair(b, L, j, diagT, sent, scnt);
    }
  }
  __threadfence();
  grid.sync();

  // ---- phase 7: greedy NMS scan (blocks 0..7, one batch each) ----
  if (bid < 8) {
    int b = bid;
    int lane = tid & 63;
    int wv = tid >> 6;
    for (int i = tid; i < NW * 64; i += 1024)
      sh.nms.diag_s[i] = diagT[(size_t)b * NW * 64 + i];
    if (tid < NW) {
      sh.nms.remv[tid] = 0ULL;
      sh.nms.cw[tid] = min(scnt[b * NW + tid], SCAP);
    }
    __syncthreads();
    if (tid == 0) {
      int run = 0;
      for (int w = 0; w < NW; ++w) { sh.nms.prefix[w] = run; run += sh.nms.cw[w]; }
      sh.nms.prefix[NW] = run;
    }
    __syncthreads();
    for (int w = wv; w < NW; w += 16) {
      const u64* gb = sent + (size_t)(b * NW + w) * SCAP * 2;
      int base = sh.nms.prefix[w], n = sh.nms.cw[w];
      for (int e = lane; e < n; e += 64) {
        int slot = base + e;
        if (slot < LDSE) {
          sh.nms.ebits[slot] = gb[e * 2];
          sh.nms.emeta[slot] = (u32)gb[e * 2 + 1];
        }
      }
    }
    __syncthreads();
    int total = 0;
    for (int w = 0; w < NW; ++w) {
      u64 rm = sh.nms.remv[w];
      u64 cmask = sh.nms.diag_s[w * 64 + lane];
      u64 validm = (w * 64 + 64 <= NSEL) ? ~0ULL : ((1ULL << (NSEL - w * 64)) - 1ULL);
      u64 A0 = ~rm & validm;
      bool alive0 = (A0 >> lane) & 1ULL;
      u64 K = __ballot(alive0);
      for (int it = 0; it < 70; ++it) {
        bool alive = alive0 && ((K & cmask) == 0ULL);
        u64 Kn = __ballot(alive);
        if (Kn == K) break;
        K = Kn;
      }
      if (tid == 0) {
        keepmask[b * NW + w] = K;
        basecnt[b * NW + w] = total;
      }
      total += __popcll(K);
      int base = sh.nms.prefix[w], n = sh.nms.cw[w];
      for (int e = tid; e < n; e += 1024) {
        int slot = base + e;
        u64 bits;
        u32 meta;
        if (slot < LDSE) {
          bits = sh.nms.ebits[slot];
          meta = sh.nms.emeta[slot];
        } else {
          const u64* ge = sent + ((size_t)(b * NW + w) * SCAP + e) * 2;
          bits = ge[0];
          meta = (u32)ge[1];
        }
        int bb = (int)(meta & 255u);
        int fw = (int)(meta >> 8);
        if ((K >> bb) & 1ULL) atomicOr(&sh.nms.remv[fw], bits);
      }
      __syncthreads();
    }
  }
  __threadfence();
  grid.sync();

  // ---- phase 8: compact kept boxes into out[b][rank] ----
  for (int t = gtid; t < BATCH * NSEL; t += gstride) {
    int b = t / NSEL, i = t - b * NSEL;
    int w = i >> 6, bb = i & 63;
    u64 K = keepmask[b * NW + w];
    if ((K >> bb) & 1ULL) {
      int rank = basecnt[b * NW + w] + __popcll(K & ((1ULL << bb) - 1ULL));
      if (rank < PROP) out[(size_t)b * PROP + rank] = boxes[(size_t)b * NPAD + i];
    }
  }
}

extern "C" void kernel_launch(void* const* d_in, const int* in_sizes, int n_in,
                              void* d_out, int out_size, void* d_ws, size_t ws_size,
                              hipStream_t stream) {
  const float* probs = (const float*)d_in[0];    // (8,131072,2)
  const float* deltas = (const float*)d_in[1];   // (8,131072,4)
  const float* anchors = (const float*)d_in[2];  // (8,131072,4)
  char* ws = (char*)d_ws;
  float4* outp = (float4*)d_out;

  void* args[] = {(void*)&probs, (void*)&deltas, (void*)&anchors,
                  (void*)&ws, (void*)&outp};
  (void)hipLaunchCooperativeKernel((void*)mega_kernel, dim3(256), dim3(1024),
                                   args, 0, stream);
}

// Round 15
// 275.961 us; speedup vs baseline: 3.5987x; 3.5987x over previous
//
#include <hip/hip_runtime.h>

#pragma clang fp contract(off)

typedef unsigned long long u64;
typedef unsigned int u32;
typedef unsigned short u16;

#define BATCH 8
#define NA 131072
#define NSEL 6000
#define NW 94                 // ceil(6000/64)
#define NPAD (NW * 64)        // 6016
#define CAND_CAP 8192
#define PROP 1000
#define SCAP 1024             // sparse entries cap per (batch, source word)
#define LDSE 6016             // sparse entries staged in LDS
#define CELLCAP 256           // boxes per 8x8 grid cell (mean ~94)
#define LARGECAP 1024         // "large" boxes per batch (dim > 1/8)
#define LTHR 0.125f

// ---- workspace layout (bytes); [0, MEMSET_BYTES) zeroed every launch ----
#define OFF_HIST     0            // BATCH*257*4 = 8224
#define OFF_BFILL    8256         // 8224 -> 16480
#define OFF_SCNT     16512        // 3008 -> 19520
#define OFF_CELLCNT  19584        // 2080 -> 21664
#define OFF_DIAGT    21696        // 385024 -> 406720
#define MEMSET_BYTES 406720
#define OFF_CAND     406720      // BATCH*8192*8 = 524288 -> 931008
#define OFF_BOXES    931008      // BATCH*6016*16 = 770048 -> 1701056
#define OFF_CELLLIST 1701056     // 262144 -> 1963200
#define OFF_LARGE    1963200     // 16384 -> 1979584
#define OFF_SENT     1979584     // 12320768 -> 14300352 (~13.6MB)

__device__ __forceinline__ int bucket_of(u32 bits) {
  u32 hi = bits >> 16;
  if (hi >= 0x3E80u && hi < 0x3F80u) return (int)(hi - 0x3E80u);
  if (hi >= 0x3F80u && hi < 0x8000u) return 255;
  return -1;
}

// "RN32(inter / max(uni,1e-12)) > 0.7f" without fp32 divide, bit-exact:
// M=0x1.666667p-1 is the 0.7f/nextafter midpoint; RN32(t)>0.7f <=> t>=M;
// a/b>=M <=> a>=M*b, exact in fp64 (25-bit x 24-bit product).
__device__ __forceinline__ bool iou_gt(float4 A, float4 B, float areaA, float areaB) {
  float iy = fminf(A.z, B.z) - fmaxf(A.x, B.x);
  float ix = fminf(A.w, B.w) - fmaxf(A.y, B.y);
  float inter = fmaxf(iy, 0.0f) * fmaxf(ix, 0.0f);
  float uni = (areaA + areaB) - inter;
  float uc = fmaxf(uni, 1e-12f);
  return (double)inter >= 0x1.666667p-1 * (double)uc;
}

__device__ __forceinline__ void emit_pair(int b, int ra, int rb, u64* diagT,
                                          u64* sent, int* scnt) {
  int src = min(ra, rb), dst = max(ra, rb);
  int wsrc = src >> 6, wdst = dst >> 6;
  if (wsrc == wdst) {
    atomicOr(&diagT[((size_t)b * NW + wdst) * 64 + (dst & 63)], 1ULL << (src & 63));
  } else {
    int e = atomicAdd(&scnt[b * NW + wsrc], 1);
    if (e < SCAP) {
      u64* p = sent + ((size_t)(b * NW + wsrc) * SCAP + e) * 2;
      p[0] = 1ULL << (dst & 63);
      p[1] = ((u64)(dst >> 6) << 8) | (u64)(src & 63);
    }
  }
}

__device__ __forceinline__ u64 shfl_xor_u64(u64 v, int lanemask) {
  u32 lo = (u32)v, hi = (u32)(v >> 32);
  lo = (u32)__shfl_xor((int)lo, lanemask);
  hi = (u32)__shfl_xor((int)hi, lanemask);
  return ((u64)hi << 32) | (u64)lo;
}

// shared helper: compute tbuck + descending bucket prefix from hist, in-block.
// Deterministic -> every block computes identical values (kills select kernel).
__device__ __forceinline__ void prefix_from_hist(const int* __restrict__ hist, int b,
                                                 int* h, int* bst, int* tb_s) {
  if (threadIdx.x < 256) h[threadIdx.x] = hist[b * 257 + threadIdx.x];
  __syncthreads();
  if (threadIdx.x == 0) {
    int run = 0, t = 0;
    bool found = false;
    for (int v = 255; v >= 0; --v) {
      bst[v] = run;
      run += h[v];
      if (!found && run >= NSEL) { t = v; found = true; }
    }
    *tb_s = t;
  }
  __syncthreads();
}

// K1: per-batch 257-bucket histogram of score high-16 bits
__global__ __launch_bounds__(256) void hist_kernel(const float* __restrict__ probs,
                                                   int* __restrict__ hist) {
  int b = blockIdx.y;
  __shared__ int h[257];
  for (int i = threadIdx.x; i < 257; i += 256) h[i] = 0;
  __syncthreads();
  int stride = gridDim.x * blockDim.x;
  for (int a = blockIdx.x * blockDim.x + threadIdx.x; a < NA; a += stride) {
    float sc = probs[((size_t)b * NA + a) * 2 + 1];
    int bk = bucket_of(__float_as_uint(sc));
    atomicAdd(&h[bk < 0 ? 256 : bk], 1);
  }
  __syncthreads();
  for (int i = threadIdx.x; i < 257; i += 256)
    if (h[i]) atomicAdd(&hist[b * 257 + i], h[i]);
}

// K2 (was K2+K3): inline select + scatter candidate keys into bucket segments
__global__ __launch_bounds__(256) void gather_kernel(const float* __restrict__ probs,
                                                     const int* __restrict__ hist,
                                                     int* __restrict__ bfill,
                                                     u64* __restrict__ cand) {
  int b = blockIdx.y;
  __shared__ int h[256];
  __shared__ int bst[256];
  __shared__ int tb_s;
  prefix_from_hist(hist, b, h, bst, &tb_s);
  int tb = tb_s;
  int stride = gridDim.x * blockDim.x;
  for (int a = blockIdx.x * blockDim.x + threadIdx.x; a < NA; a += stride) {
    float sc = probs[((size_t)b * NA + a) * 2 + 1];
    u32 bits = __float_as_uint(sc);
    int bk = bucket_of(bits);
    if (bk >= tb) {
      int pos = bst[bk] + atomicAdd(&bfill[b * 257 + bk], 1);
      if (pos < CAND_CAP)
        cand[(size_t)b * CAND_CAP + pos] = ((u64)bits << 32) | (u64)(0xFFFFFFFFu - (u32)a);
    }
  }
}

// K3 (was K4a+K4b): per-(batch,bucket-slot) bitonic sort of <=1024 keys in LDS,
// then decode+clip+bin its own ranks directly from LDS (no cand write-back).
// Block bx==0 also zeroes pad rows [NSEL, NPAD).
__global__ __launch_bounds__(256) void sortdecode_kernel(const int* __restrict__ hist,
                                                         const int* __restrict__ bfill,
                                                         const u64* __restrict__ cand,
                                                         const float* __restrict__ anchors,
                                                         const float* __restrict__ deltas,
                                                         float4* __restrict__ boxes,
                                                         int* __restrict__ cellCnt,
                                                         u16* __restrict__ cellList,
                                                         u16* __restrict__ largeList) {
  int b = blockIdx.y;
  int tid = threadIdx.x;
  __shared__ int h[256];
  __shared__ int bst[256];
  __shared__ int tb_s;
  prefix_from_hist(hist, b, h, bst, &tb_s);
  if (blockIdx.x == 0) {
    float4 z = {0.f, 0.f, 0.f, 0.f};
    for (int r = NSEL + tid; r < NPAD; r += 256) boxes[(size_t)b * NPAD + r] = z;
  }
  int v = tb_s + blockIdx.x;
  if (v > 255) return;
  int start = bst[v];
  if (start >= NSEL) return;  // ranks beyond NSEL are never consumed
  int cnt = min(min(bfill[b * 257 + v], 1024), CAND_CAP - start);
  if (cnt <= 0) return;
  const u64* seg = cand + (size_t)b * CAND_CAP + start;
  __shared__ u64 s[1024];
  u64 x[4];
#pragma unroll
  for (int p = 0; p < 4; ++p) {
    int i = p * 256 + tid;
    x[p] = (i < cnt) ? seg[i] : 0ULL;
  }
  for (int k = 2; k <= 64; k <<= 1) {
    for (int j = k >> 1; j >= 1; j >>= 1) {
#pragma unroll
      for (int p = 0; p < 4; ++p) {
        int i = p * 256 + tid;
        u64 pv = shfl_xor_u64(x[p], j);
        bool takemax = (((i & j) == 0) == ((i & k) == 0));
        u64 mx = x[p] > pv ? x[p] : pv;
        u64 mn = x[p] < pv ? x[p] : pv;
        x[p] = takemax ? mx : mn;
      }
    }
  }
#pragma unroll
  for (int p = 0; p < 4; ++p) s[p * 256 + tid] = x[p];
  __syncthreads();
  for (int k = 128; k <= 1024; k <<= 1) {
    for (int j = k >> 1; j >= 64; j >>= 1) {
      for (int q = tid; q < 512; q += 256) {
        int i = ((q & ~(j - 1)) << 1) | (q & (j - 1));
        int ixj = i | j;
        u64 a = s[i], c = s[ixj];
        bool up = ((i & k) == 0);
        if (up ? (a < c) : (a > c)) { s[i] = c; s[ixj] = a; }
      }
      __syncthreads();
    }
#pragma unroll
    for (int p = 0; p < 4; ++p) x[p] = s[p * 256 + tid];
    for (int j = 32; j >= 1; j >>= 1) {
#pragma unroll
      for (int p = 0; p < 4; ++p) {
        int i = p * 256 + tid;
        u64 pv = shfl_xor_u64(x[p], j);
        bool takemax = (((i & j) == 0) == ((i & k) == 0));
        u64 mx = x[p] > pv ? x[p] : pv;
        u64 mn = x[p] < pv ? x[p] : pv;
        x[p] = takemax ? mx : mn;
      }
    }
    __syncthreads();
#pragma unroll
    for (int p = 0; p < 4; ++p) s[p * 256 + tid] = x[p];
    __syncthreads();
  }
  // decode + clip + bin ranks [start, start+cnt) ∩ [0, NSEL)
  for (int i = tid; i < cnt; i += 256) {
    int r = start + i;
    if (r >= NSEL) continue;
    u64 key = s[i];
    float4 o = {0.f, 0.f, 0.f, 0.f};
    u32 idx = 0xFFFFFFFFu - (u32)(key & 0xFFFFFFFFu);
    if (idx < NA) {
      const float* anc = anchors + ((size_t)b * NA + idx) * 4;
      const float* dl = deltas + ((size_t)b * NA + idx) * 4;
      float y1 = anc[0], x1 = anc[1], y2 = anc[2], x2 = anc[3];
      float dy = dl[0] * 0.1f, dx = dl[1] * 0.1f;
      float dh = dl[2] * 0.2f, dw = dl[3] * 0.2f;
      float hh = y2 - y1, ww = x2 - x1;
      float cy = y1 + 0.5f * hh + dy * hh;
      float cx = x1 + 0.5f * ww + dx * ww;
      hh = hh * expf(dh);
      ww = ww * expf(dw);
      float ny1 = cy - 0.5f * hh, nx1 = cx - 0.5f * ww;
      float ny2 = ny1 + hh, nx2 = nx1 + ww;
      o.x = fminf(fmaxf(ny1, 0.f), 1.f);
      o.y = fminf(fmaxf(nx1, 0.f), 1.f);
      o.z = fminf(fmaxf(ny2, 0.f), 1.f);
      o.w = fminf(fmaxf(nx2, 0.f), 1.f);
    }
    boxes[(size_t)b * NPAD + r] = o;
    float bh = o.z - o.x, bw = o.w - o.y;
    if (bh > LTHR || bw > LTHR) {
      int pos = atomicAdd(&cellCnt[b * 65 + 64], 1);
      if (pos < LARGECAP) largeList[b * LARGECAP + pos] = (u16)r;
    } else {
      int gy = min(7, max(0, (int)((o.x + o.z) * 4.0f)));
      int gx = min(7, max(0, (int)((o.y + o.w) * 4.0f)));
      int cell = gy * 8 + gx;
      int pos = atomicAdd(&cellCnt[b * 65 + cell], 1);
      if (pos < CELLCAP) cellList[((size_t)b * 64 + cell) * CELLCAP + pos] = (u16)r;
    }
  }
}

// K4 (was K5b+K5c): blocks 0..127 = cell pair tests (round-12 v2 body);
// blocks 128..191 = large-box pair tests.
__global__ __launch_bounds__(256) void pairs_kernel(const float4* __restrict__ boxes,
                                                    const u16* __restrict__ cellList,
                                                    const u16* __restrict__ largeList,
                                                    const int* __restrict__ cellCnt,
                                                    u64* __restrict__ diagT,
                                                    u64* __restrict__ sent,
                                                    int* __restrict__ scnt) {
  int b = blockIdx.y;
  int tid = threadIdx.x;
  __shared__ float4 Ab[CELLCAP];
  __shared__ float Aa[CELLCAP];
  __shared__ int Ai[CELLCAP];
  __shared__ float4 Bb[2 * CELLCAP];
  __shared__ float Ba[2 * CELLCAP];
  __shared__ int Bi[2 * CELLCAP];
  if (blockIdx.x >= 128) {
    // large boxes vs all (large-large deduped: lower index owns pair)
    int bx2 = blockIdx.x - 128;
    int nL = min(cellCnt[b * 65 + 64], LARGECAP);
    int tot = nL * NPAD;
    int stride = 64 * 256;
    for (int t = bx2 * 256 + tid; t < tot; t += stride) {
      int li = t / NPAD;
      int j = t - li * NPAD;
      int L = largeList[b * LARGECAP + li];
      if (j == L || j >= NSEL) continue;
      float4 jb = boxes[(size_t)b * NPAD + j];
      float jh = jb.z - jb.x, jw = jb.w - jb.y;
      if ((jh > LTHR || jw > LTHR) && j < L) continue;
      float4 Lb = boxes[(size_t)b * NPAD + L];
      float La = (Lb.z - Lb.x) * (Lb.w - Lb.y);
      float ja = jh * jw;
      if (iou_gt(Lb, jb, La, ja)) emit_pair(b, L, j, diagT, sent, scnt);
    }
    return;
  }
  int c = blockIdx.x & 63;
  int sub = blockIdx.x >> 6;
  int cy = c >> 3, cx = c & 7;
  int nA = min(cellCnt[b * 65 + c], CELLCAP);
  for (int i = tid; i < nA; i += 256) {
    int r = cellList[((size_t)b * 64 + c) * CELLCAP + i];
    float4 bx = boxes[(size_t)b * NPAD + r];
    Ab[i] = bx;
    Aa[i] = (bx.z - bx.x) * (bx.w - bx.y);
    Ai[i] = r;
  }
  int dys[2], dxs[2];
  if (sub == 0) { dys[0] = 0; dxs[0] = 1; dys[1] = 1; dxs[1] = -1; }
  else         { dys[0] = 1; dxs[0] = 0; dys[1] = 1; dxs[1] = 1; }
  int nB = 0;
  for (int k = 0; k < 2; ++k) {
    int ny = cy + dys[k], nx = cx + dxs[k];
    if (ny >= 8 || nx < 0 || nx >= 8) continue;
    int nc = ny * 8 + nx;
    int cnt = min(cellCnt[b * 65 + nc], CELLCAP);
    for (int i = tid; i < cnt; i += 256) {
      int r = cellList[((size_t)b * 64 + nc) * CELLCAP + i];
      float4 bx = boxes[(size_t)b * NPAD + r];
      Bb[nB + i] = bx;
      Ba[nB + i] = (bx.z - bx.x) * (bx.w - bx.y);
      Bi[nB + i] = r;
    }
    nB += cnt;
  }
  __syncthreads();
  if (nA == 0) return;
  if (sub == 0) {  // self pairs i<j
    int s = 1;
    while ((1 << s) < nA) ++s;
    int tot = nA << s, m = (1 << s) - 1;
    for (int t = tid; t < tot; t += 256) {
      int i = t >> s, j = t & m;
      if (j < nA && i < j && iou_gt(Ab[i], Ab[j], Aa[i], Aa[j]))
        emit_pair(b, Ai[i], Ai[j], diagT, sent, scnt);
    }
  }
  if (nB) {  // cross pairs
    int s = 1;
    while ((1 << s) < nB) ++s;
    int tot = nA << s, m = (1 << s) - 1;
    for (int t = tid; t < tot; t += 256) {
      int i = t >> s, j = t & m;
      if (j < nB && iou_gt(Ab[i], Bb[j], Aa[i], Ba[j]))
        emit_pair(b, Ai[i], Bi[j], diagT, sent, scnt);
    }
  }
}

// K5 (was K6+K7): greedy NMS scan (1024 threads/batch) with fused compact.
// Parallel staging; per-step redundant Jacobi ballot fixpoint in every wave;
// keep masks + base counts stay in LDS; final loop writes out[] directly.
__global__ __launch_bounds__(1024) void nms_kernel(const u64* __restrict__ sent,
                                                   const int* __restrict__ scnt,
                                                   const u64* __restrict__ diagT,
                                                   const float4* __restrict__ boxes,
                                                   float4* __restrict__ out) {
  int b = blockIdx.x;
  int tid = threadIdx.x;
  int lane = tid & 63;
  int wv = tid >> 6;
  __shared__ u64 diag_s[NW * 64];   // 48128 B
  __shared__ u64 remv[NW];
  __shared__ u64 ebits[LDSE];       // 48128 B
  __shared__ u32 emeta[LDSE];       // 24064 B
  __shared__ int cw[NW];
  __shared__ int prefix[NW + 1];
  __shared__ u64 Kw[NW];
  __shared__ int baseW[NW];
  for (int i = tid; i < NW * 64; i += 1024)
    diag_s[i] = diagT[(size_t)b * NW * 64 + i];
  if (tid < NW) {
    remv[tid] = 0ULL;
    cw[tid] = min(scnt[b * NW + tid], SCAP);
  }
  __syncthreads();
  if (tid == 0) {
    int run = 0;
    for (int w = 0; w < NW; ++w) { prefix[w] = run; run += cw[w]; }
    prefix[NW] = run;
  }
  __syncthreads();
  for (int w = wv; w < NW; w += 16) {
    const u64* gb = sent + (size_t)(b * NW + w) * SCAP * 2;
    int base = prefix[w], n = cw[w];
    for (int e = lane; e < n; e += 64) {
      int slot = base + e;
      if (slot < LDSE) {
        ebits[slot] = gb[e * 2];
        emeta[slot] = (u32)gb[e * 2 + 1];
      }
    }
  }
  __syncthreads();
  int total = 0;
  for (int w = 0; w < NW; ++w) {
    u64 rm = remv[w];
    u64 cmask = diag_s[w * 64 + lane];
    u64 validm = (w * 64 + 64 <= NSEL) ? ~0ULL : ((1ULL << (NSEL - w * 64)) - 1ULL);
    u64 A0 = ~rm & validm;
    bool alive0 = (A0 >> lane) & 1ULL;
    u64 K = __ballot(alive0);
    for (int it = 0; it < 70; ++it) {
      bool alive = alive0 && ((K & cmask) == 0ULL);
      u64 Kn = __ballot(alive);
      if (Kn == K) break;
      K = Kn;
    }
    if (tid == 0) {
      Kw[w] = K;
      baseW[w] = total;
    }
    total += __popcll(K);
    int base = prefix[w], n = cw[w];
    for (int e = tid; e < n; e += 1024) {
      int slot = base + e;
      u64 bits;
      u32 meta;
      if (slot < LDSE) {
        bits = ebits[slot];
        meta = emeta[slot];
      } else {
        const u64* ge = sent + ((size_t)(b * NW + w) * SCAP + e) * 2;
        bits = ge[0];
        meta = (u32)ge[1];
      }
      int bb = (int)(meta & 255u);
      int fw = (int)(meta >> 8);
      if ((K >> bb) & 1ULL) atomicOr(&remv[fw], bits);
    }
    __syncthreads();
  }
  // fused compact: kept boxes (in score order) -> out[b][rank], rank<1000
  for (int i = tid; i < NSEL; i += 1024) {
    int w = i >> 6, bb = i & 63;
    u64 K = Kw[w];
    if ((K >> bb) & 1ULL) {
      int rank = baseW[w] + __popcll(K & ((1ULL << bb) - 1ULL));
      if (rank < PROP) out[(size_t)b * PROP + rank] = boxes[(size_t)b * NPAD + i];
    }
  }
}

extern "C" void kernel_launch(void* const* d_in, const int* in_sizes, int n_in,
                              void* d_out, int out_size, void* d_ws, size_t ws_size,
                              hipStream_t stream) {
  const float* probs = (const float*)d_in[0];    // (8,131072,2)
  const float* deltas = (const float*)d_in[1];   // (8,131072,4)
  const float* anchors = (const float*)d_in[2];  // (8,131072,4)
  char* ws = (char*)d_ws;
  int* hist = (int*)(ws + OFF_HIST);
  int* bfill = (int*)(ws + OFF_BFILL);
  int* scnt = (int*)(ws + OFF_SCNT);
  int* cellCnt = (int*)(ws + OFF_CELLCNT);
  u64* diagT = (u64*)(ws + OFF_DIAGT);
  u64* cand = (u64*)(ws + OFF_CAND);
  float4* boxes = (float4*)(ws + OFF_BOXES);
  u16* cellList = (u16*)(ws + OFF_CELLLIST);
  u16* largeList = (u16*)(ws + OFF_LARGE);
  u64* sent = (u64*)(ws + OFF_SENT);

  (void)hipMemsetAsync(ws, 0, MEMSET_BYTES, stream);
  (void)hipMemsetAsync(d_out, 0, (size_t)BATCH * PROP * 4 * sizeof(float), stream);

  hist_kernel<<<dim3(64, BATCH), 256, 0, stream>>>(probs, hist);
  gather_kernel<<<dim3(64, BATCH), 256, 0, stream>>>(probs, hist, bfill, cand);
  sortdecode_kernel<<<dim3(64, BATCH), 256, 0, stream>>>(hist, bfill, cand, anchors,
                                                         deltas, boxes, cellCnt,
                                                         cellList, largeList);
  pairs_kernel<<<dim3(192, BATCH), 256, 0, stream>>>(boxes, cellList, largeList,
                                                     cellCnt, diagT, sent, scnt);
  nms_kernel<<<BATCH, 1024, 0, stream>>>(sent, scnt, diagT, boxes, (float4*)d_out);
}